// Round 10
// baseline (66.120 us; speedup 1.0000x reference)
//
#include <hip/hip_runtime.h>
#include <math.h>

#define NB 8
#define NT 2048
#define NC 1024
#define DK 64
#define BT (NB*NT)

// ws layout: QKV bf16 (6,291,456 B) | attention partials (1120 slots x 8704 B)
#define QKV_BYTES  (3u * BT * DK * 2u)
#define SLOT_BYTES 8704u   // Obf[64][64] bf16 (8192) + m f32[64] (256) + l f32[64] (256)

typedef unsigned short ushort_t;
typedef unsigned int uint_t;
typedef __attribute__((ext_vector_type(8))) short short8;
typedef __attribute__((ext_vector_type(4))) float f32x4;

__device__ __forceinline__ float bf2f(uint_t u) {
    union { uint_t i; float f; } v;
    v.i = u << 16;
    return v.f;
}
__device__ __forceinline__ ushort_t f2bf(float f) {
    union { float f; uint_t i; } v; v.f = f;
    uint_t x = v.i;
    return (ushort_t)((x + 0x7fffu + ((x >> 16) & 1u)) >> 16);
}
__device__ __forceinline__ uint_t pack2bf(float lo, float hi) {
    return (uint_t)f2bf(lo) | ((uint_t)f2bf(hi) << 16);
}

// slot prefix within a batch for q-tile qt (qt>=4): sum of nseg over q'=4..qt-1,
// nseg(q') = q'/4 + 1.  140 slots per batch total.
__device__ __forceinline__ int seg_prefix(int qt) {
    const int a = qt >> 2;
    return 2 * a * (a + 1) - 4 + (qt & 3) * (a + 1);
}

// ---------------------------------------------------------------------------
// Kernel 0: W transpose+cast prep.  Wt[192][1024] bf16 in d_out scratch.
// ---------------------------------------------------------------------------
__global__ __launch_bounds__(256) void wt_prep_kernel(
    const float* __restrict__ Wq, const float* __restrict__ Wk,
    const float* __restrict__ Wv, ushort_t* __restrict__ WtG)
{
    const int tg = blockIdx.x * 256 + threadIdx.x;   // 0..24575
    const int n  = tg >> 7;                          // 0..191
    const int k0 = (tg & 127) * 8;
    const float* W = (n < 64) ? Wq : (n < 128) ? Wk : Wv;
    const int nc = n & 63;
    ushort_t o[8];
    #pragma unroll
    for (int j = 0; j < 8; ++j) o[j] = f2bf(W[(size_t)(k0 + j) * DK + nc]);
    *reinterpret_cast<uint4*>(&WtG[n * NC + k0]) = *reinterpret_cast<uint4*>(o);
}

// ---------------------------------------------------------------------------
// Kernel 1: QKV projection on MFMA — round-10: in-block K-split.
// 512 threads = 2 groups x 4 waves; group g does K-half g (8 K-steps).
// Grid 512 -> 16 waves/CU = 4 waves/SIMD (2x round-9's latency coverage).
// Partials merged via padded LDS (stride 196 f32); group 0 runs the
// epilogue (Q pre-scaled 0.125, K, V^T via LDS bounce -> coalesced stores).
// ---------------------------------------------------------------------------
__global__ __launch_bounds__(512, 4) void qkv_mfma_kernel(
    const float* __restrict__ X, const ushort_t* __restrict__ WtG,
    const float* __restrict__ bq, const float* __restrict__ bk,
    const float* __restrict__ bv, ushort_t* __restrict__ QKV)
{
    __shared__ ushort_t Xs[2][2][32 * 72];   // [group][buf]
    __shared__ float    Racc[32 * 196];      // group-1 partial (stride 196: bank-spread)
    __shared__ ushort_t VtL[64 * 40];

    const int t    = threadIdx.x;
    const int grp  = t >> 8;          // 0,1 : K-half
    const int tg   = t & 255;         // id within group
    const int w    = (t >> 6) & 3;    // col-wave within group
    const int lane = t & 63;
    const int g    = lane >> 4;
    const int col  = lane & 15;
    const int m0   = blockIdx.x * 32;
    const int kb   = grp * 512;

    const int xrow = tg >> 3;         // 0..31
    const int xc   = (tg & 7) * 8;    // 0..56

    float xf[8];
    short8 wA[6], wB[6];

    auto LOADX = [&](int k0) {
        const float4* xp = reinterpret_cast<const float4*>(
            &X[(size_t)(m0 + xrow) * NC + kb + k0 + xc]);
        float4 v0 = xp[0], v1 = xp[1];
        xf[0] = v0.x; xf[1] = v0.y; xf[2] = v0.z; xf[3] = v0.w;
        xf[4] = v1.x; xf[5] = v1.y; xf[6] = v1.z; xf[7] = v1.w;
    };
    auto LOADW = [&](int k0, short8* wn) {
        #pragma unroll
        for (int tj = 0; tj < 3; ++tj) {
            const int ng = 48 * w + 16 * tj + col;
            #pragma unroll
            for (int c = 0; c < 2; ++c)
                wn[tj * 2 + c] = *reinterpret_cast<const short8*>(
                    &WtG[ng * NC + kb + k0 + 32 * c + 8 * g]);
        }
    };
    auto WRITEX = [&](int b) {
        ushort_t xb[8];
        #pragma unroll
        for (int j = 0; j < 8; ++j) xb[j] = f2bf(xf[j]);
        *reinterpret_cast<uint4*>(&Xs[grp][b][xrow * 72 + xc]) =
            *reinterpret_cast<uint4*>(xb);
    };

    f32x4 acc[2][3];
    #pragma unroll
    for (int ri = 0; ri < 2; ++ri)
        #pragma unroll
        for (int tj = 0; tj < 3; ++tj) acc[ri][tj] = (f32x4){0.f, 0.f, 0.f, 0.f};

    auto COMPUTE = [&](int cur, short8* wc) {
        const ushort_t* XsB = Xs[grp][cur];
        #pragma unroll
        for (int c = 0; c < 2; ++c) {
            short8 af[2];
            #pragma unroll
            for (int ri = 0; ri < 2; ++ri)
                af[ri] = *reinterpret_cast<const short8*>(
                    &XsB[(16 * ri + col) * 72 + 32 * c + 8 * g]);
            #pragma unroll
            for (int ri = 0; ri < 2; ++ri)
                #pragma unroll
                for (int tj = 0; tj < 3; ++tj)
                    acc[ri][tj] = __builtin_amdgcn_mfma_f32_16x16x32_bf16(
                        af[ri], wc[tj * 2 + c], acc[ri][tj], 0, 0, 0);
        }
    };

    LOADX(0);
    LOADW(0, wA);
    WRITEX(0);

    #pragma unroll
    for (int ks2 = 0; ks2 < 4; ++ks2) {
        {   // even step
            const int ks = 2 * ks2;
            if (ks < 7) { LOADX((ks + 1) * 64); LOADW((ks + 1) * 64, wB); }
            __syncthreads();
            COMPUTE(0, wA);
            if (ks < 7) WRITEX(1);
        }
        {   // odd step
            const int ks = 2 * ks2 + 1;
            if (ks < 7) { LOADX((ks + 1) * 64); LOADW((ks + 1) * 64, wA); }
            __syncthreads();
            COMPUTE(1, wB);
            if (ks < 7) WRITEX(0);
        }
    }

    // ---- merge the two K-halves via LDS ----
    __syncthreads();
    if (grp == 1) {
        #pragma unroll
        for (int ri = 0; ri < 2; ++ri)
            #pragma unroll
            for (int tj = 0; tj < 3; ++tj)
                #pragma unroll
                for (int r = 0; r < 4; ++r)
                    Racc[(16 * ri + 4 * g + r) * 196 + 48 * w + 16 * tj + col] =
                        acc[ri][tj][r];
    }
    __syncthreads();
    if (grp == 0) {
        #pragma unroll
        for (int ri = 0; ri < 2; ++ri)
            #pragma unroll
            for (int tj = 0; tj < 3; ++tj)
                #pragma unroll
                for (int r = 0; r < 4; ++r)
                    acc[ri][tj][r] +=
                        Racc[(16 * ri + 4 * g + r) * 196 + 48 * w + 16 * tj + col];

        #pragma unroll
        for (int tj = 0; tj < 3; ++tj) {
            const int ng    = 48 * w + 16 * tj + col;
            const int which = ng >> 6, ncol = ng & 63;
            const float* bp = (which == 0) ? bq : (which == 1) ? bk : bv;
            const float bb  = bp[ncol];
            if (which == 2) {
                #pragma unroll
                for (int ri = 0; ri < 2; ++ri)
                    #pragma unroll
                    for (int r = 0; r < 4; ++r)
                        VtL[ncol * 40 + 16 * ri + 4 * g + r] = f2bf(acc[ri][tj][r] + bb);
            } else {
                const float qs = (which == 0) ? 0.125f : 1.0f;
                ushort_t* Y = QKV + (size_t)which * BT * DK;
                #pragma unroll
                for (int ri = 0; ri < 2; ++ri)
                    #pragma unroll
                    for (int r = 0; r < 4; ++r) {
                        const int rowg = m0 + 16 * ri + 4 * g + r;
                        Y[(size_t)rowg * DK + ncol] = f2bf((acc[ri][tj][r] + bb) * qs);
                    }
            }
        }
    }
    __syncthreads();
    if (grp == 0) {   // coalesced V^T store: 64 d-rows x 32 t
        ushort_t* Vt = QKV + (size_t)2 * BT * DK;
        const int d  = tg >> 2;
        const int sg = tg & 3;
        uint4 v = *reinterpret_cast<const uint4*>(&VtL[d * 40 + sg * 8]);
        *reinterpret_cast<uint4*>(&Vt[(size_t)d * BT + m0 + sg * 8]) = v;
    }
}

// ---------------------------------------------------------------------------
// Kernel 2: causal flash attention — k-segment-resident, zero hot-loop
// barriers (round 9), staging trimmed to the tiles the chunk needs.
// ---------------------------------------------------------------------------
__global__ __launch_bounds__(256) void attn_seg_kernel(
    const ushort_t* __restrict__ QKV, float* __restrict__ Out,
    char* __restrict__ Pbase)
{
    const ushort_t* Qw = QKV;
    const ushort_t* Kw = QKV + (size_t)BT * DK;
    const ushort_t* Vw = QKV + (size_t)2 * BT * DK;   // [DK][BT]

    __shared__ ushort_t Ks[256 * 72];
    __shared__ ushort_t VtL[64 * 288];

    const int t     = threadIdx.x;
    const int w     = t >> 6;
    const int lane  = t & 63;
    const int g     = lane >> 4;
    const int col   = lane & 15;
    const int batch = blockIdx.x & 7;
    const int u     = blockIdx.x >> 3;   // 0..71

    int s;
    if      (u < 16) s = 0;
    else if (u < 30) s = 1;
    else if (u < 42) s = 2;
    else if (u < 52) s = 3;
    else if (u < 60) s = 4;
    else if (u < 66) s = 5;
    else if (u < 70) s = 6;
    else             s = 7;
    const int off2 = 16 * s - s * (s - 1);
    const int qt0  = 4 * s + 2 * (u - off2);
    const int kbase = 256 * s;
    const int ntile = min(4, qt0 + 2 - 4 * s);   // k-tiles this chunk touches

    // ---- stage only the needed part of the 256-key segment ----
    {
        const int sr = t >> 2;       // 0..63
        const int ss = t & 3;        // 16-ushort segment
        for (int i = 0; i < ntile; ++i) {
            const int krow = 64 * i + sr;
            const size_t gk = ((size_t)(batch * NT) + kbase + krow) * DK + ss * 16;
            const uint4* kp = reinterpret_cast<const uint4*>(Kw + gk);
            *reinterpret_cast<uint4*>(&Ks[krow * 72 + ss * 16])     = kp[0];
            *reinterpret_cast<uint4*>(&Ks[krow * 72 + ss * 16 + 8]) = kp[1];
            const size_t gv = (size_t)sr * BT + (batch * NT + kbase + 64 * i) + ss * 16;
            const uint4* vp = reinterpret_cast<const uint4*>(Vw + gv);
            *reinterpret_cast<uint4*>(&VtL[sr * 288 + 72 * i + ss * 16])     = vp[0];
            *reinterpret_cast<uint4*>(&VtL[sr * 288 + 72 * i + ss * 16 + 8]) = vp[1];
        }
    }
    __syncthreads();   // the ONLY barrier

    #pragma unroll
    for (int iq = 0; iq < 2; ++iq) {
        const int qt   = qt0 + iq;
        const int qrow = qt * 64 + 16 * w + col;
        const int kcnt = min(4, qt - 4 * s + 1);
        const int diag = qt - 4 * s;

        short8 qf0, qf1;
        {
            const ushort_t* Qrow = Qw + ((size_t)(batch * NT) + qrow) * DK;
            qf0 = *reinterpret_cast<const short8*>(Qrow + 8 * g);
            qf1 = *reinterpret_cast<const short8*>(Qrow + 32 + 8 * g);
        }

        f32x4 Oa[4];
        #pragma unroll
        for (int dt = 0; dt < 4; ++dt) Oa[dt] = (f32x4){0.f, 0.f, 0.f, 0.f};
        float m = -INFINITY, l = 0.0f;

        for (int ktl = 0; ktl < kcnt; ++ktl) {
            f32x4 sa[4];
            #pragma unroll
            for (int tj = 0; tj < 4; ++tj) sa[tj] = (f32x4){0.f, 0.f, 0.f, 0.f};
            #pragma unroll
            for (int tj = 0; tj < 4; ++tj) {
                const ushort_t* kb = &Ks[(64 * ktl + col + 16 * tj) * 72 + 8 * g];
                short8 kf0 = *reinterpret_cast<const short8*>(kb);
                short8 kf1 = *reinterpret_cast<const short8*>(kb + 32);
                sa[tj] = __builtin_amdgcn_mfma_f32_16x16x32_bf16(kf0, qf0, sa[tj], 0, 0, 0);
                sa[tj] = __builtin_amdgcn_mfma_f32_16x16x32_bf16(kf1, qf1, sa[tj], 0, 0, 0);
            }

            float sv[4][4];
            #pragma unroll
            for (int tj = 0; tj < 4; ++tj)
                #pragma unroll
                for (int r = 0; r < 4; ++r) sv[tj][r] = sa[tj][r];

            if (ktl == diag) {
                const int s0 = (kbase + 64 * ktl);
                #pragma unroll
                for (int tj = 0; tj < 4; ++tj)
                    #pragma unroll
                    for (int r = 0; r < 4; ++r)
                        if (s0 + 16 * tj + 4 * g + r > qrow) sv[tj][r] = -INFINITY;
            }

            float vmax = sv[0][0];
            #pragma unroll
            for (int tj = 0; tj < 4; ++tj)
                #pragma unroll
                for (int r = 0; r < 4; ++r) vmax = fmaxf(vmax, sv[tj][r]);
            vmax = fmaxf(vmax, __shfl_xor(vmax, 16, 64));
            vmax = fmaxf(vmax, __shfl_xor(vmax, 32, 64));

            const float mn = fmaxf(m, vmax);
            const float sc = __expf(m - mn);
            m = mn;

            float p[4][4];
            float lt = 0.f;
            #pragma unroll
            for (int tj = 0; tj < 4; ++tj)
                #pragma unroll
                for (int r = 0; r < 4; ++r) {
                    p[tj][r] = __expf(sv[tj][r] - mn);
                    lt += p[tj][r];
                }
            lt += __shfl_xor(lt, 16, 64);
            lt += __shfl_xor(lt, 32, 64);
            l = l * sc + lt;

            float sco[4];
            #pragma unroll
            for (int r = 0; r < 4; ++r) sco[r] = __shfl(sc, 20 * g + r, 64);
            #pragma unroll
            for (int dt = 0; dt < 4; ++dt)
                #pragma unroll
                for (int r = 0; r < 4; ++r) Oa[dt][r] *= sco[r];

            uint_t pk0[4], pk1[4];
            #pragma unroll
            for (int tj = 0; tj < 4; ++tj) {
                pk0[tj] = pack2bf(p[tj][0], p[tj][1]);
                pk1[tj] = pack2bf(p[tj][2], p[tj][3]);
            }
            const int sA = col + 32 * (g & 1);
            const int sB = sA + 16;
            const bool hi = (g >= 2);

            #pragma unroll
            for (int c = 0; c < 2; ++c) {
                uint_t w0a = __shfl(pk0[2*c], sA, 64), w0b = __shfl(pk0[2*c+1], sA, 64);
                uint_t w1a = __shfl(pk1[2*c], sA, 64), w1b = __shfl(pk1[2*c+1], sA, 64);
                uint_t w2a = __shfl(pk0[2*c], sB, 64), w2b = __shfl(pk0[2*c+1], sB, 64);
                uint_t w3a = __shfl(pk1[2*c], sB, 64), w3b = __shfl(pk1[2*c+1], sB, 64);
                uint_t pa[4];
                pa[0] = hi ? w0b : w0a;
                pa[1] = hi ? w1b : w1a;
                pa[2] = hi ? w2b : w2a;
                pa[3] = hi ? w3b : w3a;
                short8 paf = *reinterpret_cast<const short8*>(pa);
                #pragma unroll
                for (int dt = 0; dt < 4; ++dt) {
                    short8 vf = *reinterpret_cast<const short8*>(
                        &VtL[(col + 16 * dt) * 288 + 72 * ktl + 32 * c + 8 * g]);
                    Oa[dt] = __builtin_amdgcn_mfma_f32_16x16x32_bf16(paf, vf, Oa[dt], 0, 0, 0);
                }
            }
        }

        float lr[4];
        #pragma unroll
        for (int r = 0; r < 4; ++r) lr[r] = __shfl(l, 20 * g + r, 64);

        if (qt < 4) {
            #pragma unroll
            for (int r = 0; r < 4; ++r) {
                const float inv = 1.0f / lr[r];
                const int row = qt * 64 + 16 * w + 4 * g + r;
                float* op = Out + ((size_t)(batch * NT) + row) * DK + col;
                #pragma unroll
                for (int dt = 0; dt < 4; ++dt) op[16 * dt] = Oa[dt][r] * inv;
            }
        } else {
            float mr[4];
            #pragma unroll
            for (int r = 0; r < 4; ++r) mr[r] = __shfl(m, 20 * g + r, 64);
            const int slot = batch * 140 + seg_prefix(qt) + s;
            char* sp = Pbase + (size_t)slot * SLOT_BYTES;
            ushort_t* Ob  = reinterpret_cast<ushort_t*>(sp);
            float*    Pm  = reinterpret_cast<float*>(sp + 8192);
            float*    Plv = reinterpret_cast<float*>(sp + 8448);
            #pragma unroll
            for (int r = 0; r < 4; ++r) {
                const int rloc = 16 * w + 4 * g + r;
                #pragma unroll
                for (int dt = 0; dt < 4; ++dt)
                    Ob[rloc * 64 + 16 * dt + col] = f2bf(Oa[dt][r]);
                if (col == 0) { Pm[rloc] = mr[r]; Plv[rloc] = lr[r]; }
            }
        }
    }
}

// ---------------------------------------------------------------------------
// Kernel 3: combine partial segments (unchanged).
// ---------------------------------------------------------------------------
__global__ __launch_bounds__(256) void attn_combine_kernel(
    const char* __restrict__ Pbase, float* __restrict__ Out)
{
    const int bid   = blockIdx.x;       // 0..223
    const int batch = bid / 28;
    const int qt    = 4 + bid % 28;
    const int nseg  = (qt >> 2) + 1;    // 2..8
    const int slot0 = batch * 140 + seg_prefix(qt);

    const int t   = threadIdx.x;
    const int row = t >> 2;
    const int d0  = (t & 3) * 16;

    float ms[8], ls[8];
    float M = -INFINITY;
    #pragma unroll
    for (int s = 0; s < 8; ++s)
        if (s < nseg) {
            const char* sp = Pbase + (size_t)(slot0 + s) * SLOT_BYTES;
            ms[s] = reinterpret_cast<const float*>(sp + 8192)[row];
            ls[s] = reinterpret_cast<const float*>(sp + 8448)[row];
            M = fmaxf(M, ms[s]);
        }

    float acc[16];
    #pragma unroll
    for (int j = 0; j < 16; ++j) acc[j] = 0.f;
    float ltot = 0.f;

    #pragma unroll
    for (int s = 0; s < 8; ++s)
        if (s < nseg) {
            const float wsc = __expf(ms[s] - M);
            ltot += wsc * ls[s];
            const ushort_t* Ob = reinterpret_cast<const ushort_t*>(
                Pbase + (size_t)(slot0 + s) * SLOT_BYTES) + row * 64 + d0;
            uint4 u0 = *reinterpret_cast<const uint4*>(Ob);
            uint4 u1 = *reinterpret_cast<const uint4*>(Ob + 8);
            const uint_t* uu = reinterpret_cast<const uint_t*>(&u0);
            #pragma unroll
            for (int j = 0; j < 4; ++j) {
                acc[2*j+0] += wsc * bf2f(uu[j] & 0xffffu);
                acc[2*j+1] += wsc * bf2f(uu[j] >> 16);
            }
            const uint_t* uv = reinterpret_cast<const uint_t*>(&u1);
            #pragma unroll
            for (int j = 0; j < 4; ++j) {
                acc[8+2*j+0] += wsc * bf2f(uv[j] & 0xffffu);
                acc[8+2*j+1] += wsc * bf2f(uv[j] >> 16);
            }
        }

    const float inv = 1.0f / ltot;
    float* op = Out + ((size_t)(batch * NT) + qt * 64 + row) * DK + d0;
    #pragma unroll
    for (int j = 0; j < 16; ++j) op[j] = acc[j] * inv;
}

extern "C" void kernel_launch(void* const* d_in, const int* in_sizes, int n_in,
                              void* d_out, int out_size, void* d_ws, size_t ws_size,
                              hipStream_t stream) {
    const float* X  = (const float*)d_in[0];
    const float* Wq = (const float*)d_in[1];
    const float* bq = (const float*)d_in[2];
    const float* Wk = (const float*)d_in[3];
    const float* bk = (const float*)d_in[4];
    const float* Wv = (const float*)d_in[5];
    const float* bv = (const float*)d_in[6];
    float* Out = (float*)d_out;
    ushort_t* QKV = (ushort_t*)d_ws;                 // Q | K | V^T, each BT*DK bf16
    char* Pbase   = (char*)d_ws + QKV_BYTES;         // 1120 slots x 8704 B (~9.7 MB)
    ushort_t* WtG = (ushort_t*)d_out;                // Wt scratch, overwritten by attn

    wt_prep_kernel<<<96, 256, 0, stream>>>(Wq, Wk, Wv, WtG);
    qkv_mfma_kernel<<<512, 512, 0, stream>>>(X, WtG, bq, bk, bv, QKV);
    attn_seg_kernel<<<576, 256, 0, stream>>>(QKV, Out, Pbase);
    attn_combine_kernel<<<224, 256, 0, stream>>>(Pbase, Out);
}